// Round 12
// baseline (1160.231 us; speedup 1.0000x reference)
//
#include <hip/hip_runtime.h>
#include <hip/hip_bf16.h>

typedef __bf16 bf16;
typedef __bf16 bf16x4 __attribute__((ext_vector_type(4)));
typedef __bf16 bf16x8 __attribute__((ext_vector_type(8)));
typedef float f32x4 __attribute__((ext_vector_type(4)));

constexpr int kN = 50000;      // nodes
constexpr int kE = 100000;     // edges
constexpr int kD = 300;        // node dim / per-head dim
constexpr int kH = 4;          // heads
constexpr int kHC = 1200;      // kH*kD
constexpr int kK1A = 304;      // xpad row stride (bf16): 608B, 16B-aligned
constexpr int kK1B = 320;      // W1 K padded: cols k>=300 zero => kills A tail garbage
constexpr int kNP1 = 2432;     // pass-1 N (skip|v: 2*1200 -> 19*128)
constexpr int kNZ  = 1280;     // pass-0 N (Z 1200 + T 24 -> 10*128)
constexpr int kTW  = 24;       // T buffer width (4 heads x 6 cols)
constexpr int kMP = 50048;     // M padded
constexpr int kK2 = 1216;      // K padded for GEMM2 (1200->1216)
constexpr int kN2P = 384;      // N padded for GEMM2 (300->384)
constexpr int kLY = 1216;      // bufA row stride (z/s/y)
constexpr int kNB1 = kNP1 / 128;   // 19 n-blocks (pass-1)
constexpr int kNB0 = kNZ / 128;    // 10 n-blocks (pass-0)
constexpr int kMB2 = kMP / 64;     // 782 m-blocks (64-row tiles)
constexpr int kT1 = kK1B / 32;     // 10 K-steps (GEMM1)
constexpr int kNB2 = kN2P / 128;   // 3 n-blocks (GEMM2)
constexpr int kT2 = kK2 / 32;      // 38 K-steps (GEMM2)
constexpr int kWG1 = kMB2 * kNB1;  // 14858 blocks (pass-1)
constexpr int kWG0 = kMB2 * kNB0;  // 7820 blocks (pass-0)
constexpr int kWG2 = kMB2 * kNB2;  // 2346 blocks (GEMM2)
constexpr int kEW = 136;           // epilogue LDS row stride
// xpad split: rows < kSplitRow in d_out, rest in ws region unioned with cnt/fill
constexpr int kSplitRow = 49342;             // 49342*608 = 29,999,936 <= 30,000,000
constexpr size_t kXhiBytes = (size_t)(kN + 1 - kSplitRow) * kK1A * 2;  // 400,672

// ---- dtype-agnostic loads (flags[0]: floats are fp32; flags[1]: ints are int64)
__device__ __forceinline__ float ldF(const void* p, size_t i, int f32) {
    return f32 ? ((const float*)p)[i] : (float)((const bf16*)p)[i];
}
__device__ __forceinline__ int ldI(const void* p, size_t i, int i64) {
    return i64 ? ((const int*)p)[2 * i] : ((const int*)p)[i];
}

// split-xpad row pointer
__device__ __forceinline__ const bf16* xrow(const bf16* lo, const bf16* hi, int r) {
    return r < kSplitRow ? lo + (size_t)r * kK1A : hi + (size_t)(r - kSplitRow) * kK1A;
}
__device__ __forceinline__ bf16* xrow_w(bf16* lo, bf16* hi, int r) {
    return r < kSplitRow ? lo + (size_t)r * kK1A : hi + (size_t)(r - kSplitRow) * kK1A;
}

// ---- async global->LDS, 16B per lane. LDS dest = wave-uniform base + lane*16.
__device__ __forceinline__ void glds16(const void* g, void* l) {
    __builtin_amdgcn_global_load_lds((const __attribute__((address_space(1))) void*)g,
                                     (__attribute__((address_space(3))) void*)l, 16, 0, 0);
}

// ---- XCD-aware bijective block swizzle (T1, m204)
template <int NWG>
__device__ __forceinline__ int xcd_swz(int phys) {
    constexpr int q = NWG >> 3, r = NWG & 7;
    int xcd = phys & 7, i = phys >> 3;
    int base = xcd < r ? xcd * (q + 1) : r * (q + 1) + (xcd - r) * q;
    return base + i;
}

// ---- bf16-pair (u32) helpers
__device__ __forceinline__ float bflo(unsigned u) {
    return __builtin_bit_cast(float, u << 16);
}
__device__ __forceinline__ float bfhi(unsigned u) {
    return __builtin_bit_cast(float, u & 0xFFFF0000u);
}
__device__ __forceinline__ unsigned bfpack(float a, float b) {
    bf16 x = (bf16)a, y = (bf16)b;
    unsigned short ux = __builtin_bit_cast(unsigned short, x);
    unsigned short uy = __builtin_bit_cast(unsigned short, y);
    return (unsigned)ux | ((unsigned)uy << 16);
}
// wave-wide sum, result on all lanes
__device__ __forceinline__ float wsum(float v) {
#pragma unroll
    for (int o = 32; o > 0; o >>= 1) v += __shfl_xor(v, o);
    return v;
}

// ---------------- dtype detector (device-side, graph-safe) ----------------
__global__ void detect_kernel(const unsigned short* __restrict__ xin_u,
                              const int* __restrict__ eidx_i,
                              int* __restrict__ flags) {
    __shared__ int s_ff, s_nz;
    if (threadIdx.x == 0) { s_ff = 0; s_nz = 0; }
    __syncthreads();
    int c1 = 0;
    for (int i = threadIdx.x; i < 65536; i += 256)
        c1 += (((xin_u[i] >> 7) & 0xFF) == 0xFF);   // bf16-view exp==0xFF => data is fp32
    int c2 = 0;
    for (int i = threadIdx.x; i < 1024; i += 256)
        c2 += (eidx_i[2 * i + 1] != 0);             // odd words all zero => int64
    atomicAdd(&s_ff, c1);
    atomicAdd(&s_nz, c2);
    __syncthreads();
    if (threadIdx.x == 0) {
        flags[0] = (s_ff > 0) ? 1 : 0;
        flags[1] = (s_nz == 0) ? 1 : 0;
    }
}

// ---------------- merged small-casts ----------------
__global__ void cast5(const void* __restrict__ We, const void* __restrict__ be,
                      const void* __restrict__ lna, const void* __restrict__ lnb,
                      const void* __restrict__ blin, float* __restrict__ Wef,
                      float* __restrict__ bef, float* __restrict__ lnaf,
                      float* __restrict__ lnbf, float* __restrict__ blinf,
                      const int* __restrict__ flags) {
    int i = blockIdx.x * 256 + threadIdx.x;
    int f32 = flags[0];
    if (i < 4 * kHC) { Wef[i] = ldF(We, i, f32); return; }
    i -= 4 * kHC;
    if (i < kHC) { bef[i] = ldF(be, i, f32); return; }
    i -= kHC;
    if (i < kHC) { lnaf[i] = ldF(lna, i, f32); return; }
    i -= kHC;
    if (i < kHC) { lnbf[i] = ldF(lnb, i, f32); return; }
    i -= kHC;
    if (i < kD) blinf[i] = ldF(blin, i, f32);
}

// ---------------- xin -> bf16 split-padded [kN+1][304] ----------------
__global__ void cast_xpad(const void* __restrict__ xin, bf16* __restrict__ xlo,
                          bf16* __restrict__ xhi, const int* __restrict__ flags) {
    int idx = blockIdx.x * 256 + threadIdx.x;      // one thread per 4-col chunk
    if (idx < 4) {   // 32B zero guard past last d_out row
        bf16x4 z = {};
        *(bf16x4*)&xlo[(size_t)kSplitRow * kK1A + idx * 4] = z;
    }
    if (idx >= (kN + 1) * 76) return;
    int r = idx / 76, c4 = idx % 76;
    int c = c4 * 4;
    bf16x4 w = {};
    if (r < kN && c < kD) {                         // cols 300..303 and row kN stay 0
        int f32 = flags[0];
        size_t b = (size_t)r * kD + c;
        w[0] = (bf16)ldF(xin, b + 0, f32);
        w[1] = (bf16)ldF(xin, b + 1, f32);
        w[2] = (bf16)ldF(xin, b + 2, f32);
        w[3] = (bf16)ldF(xin, b + 3, f32);
    }
    *(bf16x4*)&(xrow_w(xlo, xhi, r)[c]) = w;        // 8B-aligned (stride 608B)
}

// ---------------- bilinear precompute: M_h = Wq_h Wk_h^T ----------------
// M[h][d][dp] = sum_c Wq[d][h*300+c] * Wk[dp][h*300+c]; fp32 scratch [4][300][304]
__global__ void compute_M(const void* __restrict__ Wq, const void* __restrict__ Wk,
                          float* __restrict__ Mscr, const int* __restrict__ flags) {
    int b = blockIdx.x;                 // 4 * 19 * 19 blocks
    int h = b / 361, t2 = b % 361;
    int ty = t2 / 19, tx = t2 % 19;
    int r = threadIdx.x >> 4, c = threadIdx.x & 15;
    int d = ty * 16 + r, dp = tx * 16 + c;
    if (d >= 300 || dp >= 304) return;
    float s = 0.f;
    if (dp < 300) {
        int f32 = flags[0];
#pragma unroll 4
        for (int cc = 0; cc < 300; ++cc)
            s += ldF(Wq, (size_t)d * kHC + h * 300 + cc, f32) *
                 ldF(Wk, (size_t)dp * kHC + h * 300 + cc, f32);
    }
    Mscr[((size_t)h * 300 + d) * 304 + dp] = s;
}

// ---------------- U vectors + w3 + constants for exact bias handling --------
// Uscr[h*6+j][d]: j<4: Wq_h^T We_j,h;  j=4: Wq_h^T be_h;  j=5: Wq_h^T bk_h.
// w3scr[h][d] = sum_c bq[hc+c]*Wk[d][hc+c].  cst8[h*8+j]: j<4 bq.We_j, 4 bq.be, 5 bq.bk.
__global__ void compute_U(const void* __restrict__ Wq, const void* __restrict__ Wk,
                          const void* __restrict__ We, const void* __restrict__ be,
                          const void* __restrict__ bq, const void* __restrict__ bk,
                          float* __restrict__ Uscr, float* __restrict__ w3scr,
                          float* __restrict__ cst8, const int* __restrict__ flags) {
    int t = blockIdx.x * 256 + threadIdx.x;
    int f32 = flags[0];
    if (t < 24 * 304) {
        int vi = t / 304, d = t % 304;
        int h = vi / 6, j = vi % 6;
        float s = 0.f;
        if (d < 300) {
#pragma unroll 4
            for (int c = 0; c < 300; ++c) {
                float a = ldF(Wq, (size_t)d * kHC + h * 300 + c, f32);
                float b = (j < 4) ? ldF(We, (size_t)j * kHC + h * 300 + c, f32)
                        : (j == 4) ? ldF(be, h * 300 + c, f32)
                                   : ldF(bk, h * 300 + c, f32);
                s += a * b;
            }
        }
        Uscr[t] = s;
        return;
    }
    t -= 24 * 304;
    if (t < 4 * 304) {
        int h = t / 304, d = t % 304;
        float s = 0.f;
        if (d < 300) {
#pragma unroll 4
            for (int c = 0; c < 300; ++c)
                s += ldF(bq, h * 300 + c, f32) * ldF(Wk, (size_t)d * kHC + h * 300 + c, f32);
        }
        w3scr[t] = s;
        return;
    }
    t -= 4 * 304;
    if (t < 24) {
        int h = t / 6, j = t % 6;
        float s = 0.f;
#pragma unroll 4
        for (int c = 0; c < 300; ++c) {
            float a = ldF(bq, h * 300 + c, f32);
            float b = (j < 4) ? ldF(We, (size_t)j * kHC + h * 300 + c, f32)
                    : (j == 4) ? ldF(be, h * 300 + c, f32)
                               : ldF(bk, h * 300 + c, f32);
            s += a * b;
        }
        cst8[h * 8 + j] = s;
    }
}

// ---------------- pack Z/T panel (frag-major) from M/U scratch --------------
__global__ void pack_Zf(const float* __restrict__ Mscr, const float* __restrict__ Uscr,
                        bf16* __restrict__ Bf) {
    int idx = blockIdx.x * 256 + threadIdx.x;
    if (idx >= kNB0 * kT1 * 8 * 64) return;
    int lane = idx & 63;
    int fi = (idx >> 6) & 7;
    int ksnb = idx >> 9;
    int ks = ksnb % kT1;
    int nb = ksnb / kT1;
    int n = nb * 128 + fi * 16 + (lane & 15);
    int kbase = ks * 32 + (lane >> 4) * 8;
    bf16x8 w = {};
#pragma unroll
    for (int e = 0; e < 8; ++e) {
        int k = kbase + e;
        float v = 0.f;
        if (k < 300) {
            if (n < kHC) {
                int h = n / 300, dp = n % 300;
                v = Mscr[((size_t)h * 300 + k) * 304 + dp];
            } else if (n < kHC + kTW) {
                v = Uscr[(size_t)(n - kHC) * 304 + k];
            }
        }
        w[e] = (bf16)v;
    }
    *(bf16x8*)&Bf[(size_t)idx * 8] = w;
}

// ---------------- pass-1 weight pack (skip|v, frag-major) -------------------
__global__ void pack_W1f(const void* __restrict__ Ws, const void* __restrict__ Wv,
                         bf16* __restrict__ Bf, const int* __restrict__ flags) {
    int idx = blockIdx.x * 256 + threadIdx.x;
    if (idx >= kNB1 * kT1 * 8 * 64) return;
    int f32 = flags[0];
    int lane = idx & 63;
    int fi = (idx >> 6) & 7;
    int ksnb = idx >> 9;
    int ks = ksnb % kT1;
    int nb = ksnb / kT1;
    int n = nb * 128 + fi * 16 + (lane & 15);
    int kbase = ks * 32 + (lane >> 4) * 8;
    const void* W = nullptr;
    int c = 0;
    if (n < kHC)          { W = Ws; c = n; }
    else if (n < 2 * kHC) { W = Wv; c = n - kHC; }
    bf16x8 w = {};
#pragma unroll
    for (int e = 0; e < 8; ++e) {
        int k = kbase + e;
        float v = 0.f;
        if (W && k < kD) v = ldF(W, (size_t)k * kHC + c, f32);
        w[e] = (bf16)v;
    }
    *(bf16x8*)&Bf[(size_t)idx * 8] = w;
}

__global__ void pack_W2f(const void* __restrict__ Wlin, bf16* __restrict__ Bf,
                         const int* __restrict__ flags) {
    int idx = blockIdx.x * 256 + threadIdx.x;
    if (idx >= kNB2 * kT2 * 8 * 64) return;
    int f32 = flags[0];
    int lane = idx & 63;
    int fi = (idx >> 6) & 7;
    int ksnb = idx >> 9;
    int ks = ksnb % kT2;
    int nb = ksnb / kT2;
    int n = nb * 128 + fi * 16 + (lane & 15);
    int kbase = ks * 32 + (lane >> 4) * 8;
    bf16x8 w = {};
#pragma unroll
    for (int e = 0; e < 8; ++e) {
        int k = kbase + e;
        float v = 0.f;
        if (n < kD && k < kHC) v = ldF(Wlin, (size_t)k * kD + n, f32);
        w[e] = (bf16)v;
    }
    *(bf16x8*)&Bf[(size_t)idx * 8] = w;
}

__global__ void pack_bias(const void* __restrict__ bs, const void* __restrict__ bv,
                          float* __restrict__ bcat, const int* __restrict__ flags) {
    int n = blockIdx.x * 256 + threadIdx.x;
    if (n >= kNP1) return;
    int f32 = flags[0];
    float v = 0.f;
    if (n < kHC)          v = ldF(bs, n, f32);
    else if (n < 2 * kHC) v = ldF(bv, n - kHC, f32);
    bcat[n] = v;
}

// ---------------- CSR build (dst-sorted edges) ----------------
__global__ void hist_kernel(const void* __restrict__ eidx, int* __restrict__ cnt,
                            const int* __restrict__ flags) {
    int e = blockIdx.x * 256 + threadIdx.x;
    if (e < kE) atomicAdd(&cnt[ldI(eidx, (size_t)kE + e, flags[1])], 1);
}

__global__ void scan_local(const int* __restrict__ cnt, int* __restrict__ rowptr,
                           int* __restrict__ bsum) {
    int b = blockIdx.x, t = threadIdx.x;
    int i = b * 256 + t;
    int v = (i < kN) ? cnt[i] : 0;
    int lane = t & 63, wv = t >> 6;
    int s = v;
#pragma unroll
    for (int o = 1; o < 64; o <<= 1) {
        int u = __shfl_up(s, o);
        if (lane >= o) s += u;
    }
    __shared__ int wtot[4];
    if (lane == 63) wtot[wv] = s;
    __syncthreads();
    int add = 0;
    for (int w = 0; w < wv; ++w) add += wtot[w];
    if (i < kN) rowptr[i] = s - v + add;
    if (t == 255) bsum[b] = add + s;
}
__global__ void scan_bsums(int* __restrict__ bsum, int nb) {
    int t = threadIdx.x;
    int v = (t < nb) ? bsum[t] : 0;
    int lane = t & 63, wv = t >> 6;
    int s = v;
#pragma unroll
    for (int o = 1; o < 64; o <<= 1) {
        int u = __shfl_up(s, o);
        if (lane >= o) s += u;
    }
    __shared__ int wtot[4];
    if (lane == 63) wtot[wv] = s;
    __syncthreads();
    int add = 0;
    for (int w = 0; w < wv; ++w) add += wtot[w];
    if (t < nb) bsum[t] = s - v + add;
}
__global__ void scan_add(int* __restrict__ rowptr, const int* __restrict__ bsum) {
    int i = blockIdx.x * 256 + threadIdx.x;
    if (i < kN) rowptr[i] += bsum[i >> 8];
    if (i == 0) rowptr[kN] = kE;
}

__global__ void scatter_kernel(const void* __restrict__ eidx, const int* __restrict__ rowptr,
                               int* __restrict__ fill, int* __restrict__ esort,
                               const int* __restrict__ flags) {
    int e = blockIdx.x * 256 + threadIdx.x;
    if (e < kE) {
        int d = ldI(eidx, (size_t)kE + e, flags[1]);
        int pos = rowptr[d] + atomicAdd(&fill[d], 1);
        esort[pos] = e;
    }
}

// ---------------- pass-0 GEMM: [Z|T] = xpad @ [M|U]  (R9-proven structure) ---
__global__ __launch_bounds__(256, 4) void gemm_z(const bf16* __restrict__ xlo,
                                                 const bf16* __restrict__ xhi,
                                                 const bf16* __restrict__ Bf,
                                                 bf16* __restrict__ outA,
                                                 bf16* __restrict__ Tb) {
    __shared__ alignas(16) bf16 As[64 * 32];
    __shared__ alignas(16) bf16 Es[64 * kEW];
    const int logical = xcd_swz<kWG0>(blockIdx.x);
    const int mb = logical / kNB0, nb = logical % kNB0;
    const int tid = threadIdx.x;
    const int lane = tid & 63, wave = tid >> 6;
    const int quad = lane >> 4, l16 = lane & 15;
    const int mw = (wave >> 1) * 32;
    const int fibase = (wave & 1) * 4;
    const f32x4 zero = {0.f, 0.f, 0.f, 0.f};
    f32x4 acc[2][4];
#pragma unroll
    for (int i = 0; i < 2; i++)
#pragma unroll
        for (int j = 0; j < 4; j++) acc[i][j] = zero;
    const int mblk = mb * 64, nblk = nb * 128;
    const int srow = wave * 16 + (lane >> 2);
    const int ss = lane & 3;
    int gr = mblk + srow; if (gr >= kN) gr = kN - 1;
    const bf16* gA = xrow(xlo, xhi, gr) + ((ss ^ ((srow >> 1) & 3)) << 3);
    bf16* lA = As + wave * 512;
    int aoff[2];
#pragma unroll
    for (int i = 0; i < 2; i++) {
        int ra = mw + i * 16 + l16;
        aoff[i] = ra * 32 + ((quad ^ ((ra >> 1) & 3)) << 3);
    }
    const bf16* bbase = Bf + (size_t)nb * (kT1 * 4096) + fibase * 512 + lane * 8;
    for (int t = 0; t < kT1; ++t) {
        __syncthreads();
        glds16(gA + t * 32, lA);
        bf16x8 bfv[4];
#pragma unroll
        for (int ni = 0; ni < 4; ni++)
            bfv[ni] = *(const bf16x8*)(bbase + (size_t)t * 4096 + ni * 512);
        __syncthreads();
        bf16x8 af[2];
#pragma unroll
        for (int i = 0; i < 2; i++) af[i] = *(const bf16x8*)&As[aoff[i]];
#pragma unroll
        for (int mi = 0; mi < 2; mi++)
#pragma unroll
            for (int ni = 0; ni < 4; ni++)
                acc[mi][ni] = __builtin_amdgcn_mfma_f32_16x16x32_bf16(
                    af[mi], bfv[ni], acc[mi][ni], 0, 0, 0);
    }
    __syncthreads();
#pragma unroll
    for (int mi = 0; mi < 2; mi++)
#pragma unroll
        for (int r = 0; r < 4; r++) {
            int lr = mw + mi * 16 + quad * 4 + r;
#pragma unroll
            for (int ni = 0; ni < 4; ni++) {
                int lc = (fibase + ni) * 16 + l16;
                Es[lr * kEW + lc] = (bf16)acc[mi][ni][r];   // no bias on Z/T
            }
        }
    __syncthreads();
#pragma unroll
    for (int it = 0; it < 4; ++it) {
        int row = it * 16 + (tid >> 4);
        int col8 = (tid & 15) * 8;
        int m = mblk + row;
        if (m >= kN) continue;
        bf16x8 w = *(const bf16x8*)&Es[row * kEW + col8];
        int n = nblk + col8;                              // 1200/1224 both %8==0
        if (n < kHC)            *(bf16x8*)&outA[(size_t)m * kLY + n] = w;
        else if (n < kHC + kTW) *(bf16x8*)&Tb[(size_t)m * kTW + (n - kHC)] = w;
    }
}

// ---------------- pass-1 GEMM: [skip|v] = xpad @ W1 + b  (R9-proven) --------
__global__ __launch_bounds__(256, 4) void gemm_qkvs(const bf16* __restrict__ xlo,
                                                    const bf16* __restrict__ xhi,
                                                    const bf16* __restrict__ Bf,
                                                    const float* __restrict__ bcat,
                                                    bf16* __restrict__ outA,
                                                    bf16* __restrict__ outB) {
    __shared__ alignas(16) bf16 As[64 * 32];
    __shared__ alignas(16) bf16 Es[64 * kEW];
    const int logical = xcd_swz<kWG1>(blockIdx.x);
    const int mb = logical / kNB1, nb = logical % kNB1;
    const int tid = threadIdx.x;
    const int lane = tid & 63, wave = tid >> 6;
    const int quad = lane >> 4, l16 = lane & 15;
    const int mw = (wave >> 1) * 32;
    const int fibase = (wave & 1) * 4;
    const f32x4 zero = {0.f, 0.f, 0.f, 0.f};
    f32x4 acc[2][4];
#pragma unroll
    for (int i = 0; i < 2; i++)
#pragma unroll
        for (int j = 0; j < 4; j++) acc[i][j] = zero;
    const int mblk = mb * 64, nblk = nb * 128;
    const int srow = wave * 16 + (lane >> 2);
    const int ss = lane & 3;
    int gr = mblk + srow; if (gr >= kN) gr = kN - 1;
    const bf16* gA = xrow(xlo, xhi, gr) + ((ss ^ ((srow >> 1) & 3)) << 3);
    bf16* lA = As + wave * 512;
    int aoff[2];
#pragma unroll
    for (int i = 0; i < 2; i++) {
        int ra = mw + i * 16 + l16;
        aoff[i] = ra * 32 + ((quad ^ ((ra >> 1) & 3)) << 3);
    }
    const bf16* bbase = Bf + (size_t)nb * (kT1 * 4096) + fibase * 512 + lane * 8;
    for (int t = 0; t < kT1; ++t) {
        __syncthreads();
        glds16(gA + t * 32, lA);
        bf16x8 bfv[4];
#pragma unroll
        for (int ni = 0; ni < 4; ni++)
            bfv[ni] = *(const bf16x8*)(bbase + (size_t)t * 4096 + ni * 512);
        __syncthreads();
        bf16x8 af[2];
#pragma unroll
        for (int i = 0; i < 2; i++) af[i] = *(const bf16x8*)&As[aoff[i]];
#pragma unroll
        for (int mi = 0; mi < 2; mi++)
#pragma unroll
            for (int ni = 0; ni < 4; ni++)
                acc[mi][ni] = __builtin_amdgcn_mfma_f32_16x16x32_bf16(
                    af[mi], bfv[ni], acc[mi][ni], 0, 0, 0);
    }
    __syncthreads();
#pragma unroll
    for (int mi = 0; mi < 2; mi++)
#pragma unroll
        for (int r = 0; r < 4; r++) {
            int lr = mw + mi * 16 + quad * 4 + r;
#pragma unroll
            for (int ni = 0; ni < 4; ni++) {
                int lc = (fibase + ni) * 16 + l16;
                Es[lr * kEW + lc] = (bf16)(acc[mi][ni][r] + bcat[nblk + lc]);
            }
        }
    __syncthreads();
#pragma unroll
    for (int it = 0; it < 4; ++it) {
        int row = it * 16 + (tid >> 4);
        int col8 = (tid & 15) * 8;
        int m = mblk + row;
        if (m >= kN) continue;
        bf16x8 w = *(const bf16x8*)&Es[row * kEW + col8];
        int n = nblk + col8;
        if (n < kHC)          *(bf16x8*)&outA[(size_t)m * kLY + n] = w;
        else if (n < 2 * kHC) *(bf16x8*)&outB[(size_t)m * kHC + (n - kHC)] = w;
    }
}

// ---------------- node_alpha (bilinear form): gather x_src (600B, L3-hot) ----
// logit = z_dst.x_src + w3.x_src + (t5+c5) + sum_j ea_j*(t_j+c_j) + (t4+c4)
// == q.(k+ee) exactly (biases folded via T cols + consts).
__global__ __launch_bounds__(256) void node_alpha(const int* __restrict__ rowptr,
                                                  const int* __restrict__ esort,
                                                  const void* __restrict__ eidx,
                                                  const void* __restrict__ eattr,
                                                  bf16* __restrict__ qb,
                                                  const bf16* __restrict__ xlo,
                                                  const bf16* __restrict__ xhi,
                                                  const bf16* __restrict__ Tb,
                                                  const float* __restrict__ w3scr,
                                                  const float* __restrict__ cst8,
                                                  float* __restrict__ alpha,
                                                  const int* __restrict__ flags) {
    int i = blockIdx.x;
    int h = threadIdx.x >> 6, lane = threadIdx.x & 63;
    int r0 = rowptr[i], r1 = rowptr[i + 1];
    if (r0 >= r1) return;                    // node_fused guards inv by degree
    int f32 = flags[0], i64 = flags[1];
    const unsigned* zr = (const unsigned*)(qb + (size_t)i * kLY + h * kD);
    float z0[3], z1[3], w30[3], w31[3];
#pragma unroll
    for (int j = 0; j < 3; ++j) {
        int p = lane + 64 * j;
        unsigned u = (p < 150) ? zr[p] : 0u;
        z0[j] = bflo(u); z1[j] = bfhi(u);
        if (p < 150) {
            w30[j] = w3scr[h * 304 + 2 * p];
            w31[j] = w3scr[h * 304 + 2 * p + 1];
        } else { w30[j] = 0.f; w31[j] = 0.f; }
    }
    const bf16* tr = Tb + (size_t)i * kTW + h * 6;
    const float* cc = cst8 + h * 8;
    float tj0 = (float)tr[0] + cc[0], tj1 = (float)tr[1] + cc[1];
    float tj2 = (float)tr[2] + cc[2], tj3 = (float)tr[3] + cc[3];
    float base = ((float)tr[4] + cc[4]) + ((float)tr[5] + cc[5]);
    float denom = 0.f;
    for (int p = r0; p < r1; ++p) {
        int e = esort[p];
        int src = ldI(eidx, e, i64);
        float ea0 = ldF(eattr, (size_t)e * 4 + 0, f32), ea1 = ldF(eattr, (size_t)e * 4 + 1, f32);
        float ea2 = ldF(eattr, (size_t)e * 4 + 2, f32), ea3 = ldF(eattr, (size_t)e * 4 + 3, f32);
        const unsigned* xr = (const unsigned*)xrow(xlo, xhi, src);
        float s = 0.f;
#pragma unroll
        for (int j = 0; j < 3; ++j) {
            int pp = lane + 64 * j;
            if (pp < 150) {
                unsigned u = xr[pp];
                float xa = bflo(u), xb = bfhi(u);
                s += (z0[j] + w30[j]) * 0.f;  // placeholder removed below
                s += z0[j] * xa + z1[j] * xb + w30[j] * xa + w31[j] * xb;
            }
        }
        float dot = wsum(s);
        float logit = dot + base + ea0 * tj0 + ea1 * tj1 + ea2 * tj2 + ea3 * tj3;
        float a = expf(logit * 0.05773502691896258f);   // 1/sqrt(300)
        if (lane == 0) alpha[e * kH + h] = a;
        denom += a;                                     // wave-uniform
    }
    if (lane == 0)
        ((float*)(qb + (size_t)i * kLY + kHC))[h] = 1.f / (denom + 1e-16f);
}

// ---------------- fused: aggregate + skip + LayerNorm (unchanged, proven) ----
__global__ __launch_bounds__(256) void node_fused(const int* __restrict__ rowptr,
                                                  const int* __restrict__ esort,
                                                  const void* __restrict__ eidx,
                                                  const void* __restrict__ eattr,
                                                  const float* __restrict__ Wef,
                                                  const float* __restrict__ bef,
                                                  const float* __restrict__ alpha,
                                                  const bf16* __restrict__ vb,
                                                  const float* __restrict__ lnaf,
                                                  const float* __restrict__ lnbf,
                                                  bf16* __restrict__ qy,
                                                  const int* __restrict__ flags) {
    int i = blockIdx.x;
    int t = threadIdx.x, h = t >> 6, lane = t & 63;
    bf16* yr = qy + (size_t)i * kLY;
    if (i >= kN) {
        for (int c = t; c < kK2; c += 256) yr[c] = (bf16)0.f;
        return;
    }
    int f32 = flags[0], i64 = flags[1];
    int r0 = rowptr[i], r1 = rowptr[i + 1];
    float inv = (r1 > r0) ? ((const float*)(yr + kHC))[h] : 0.f;
    unsigned* yr32 = (unsigned*)(yr + h * kD);
    float a0[3], a1[3];
#pragma unroll
    for (int j = 0; j < 3; ++j) {
        int p = lane + 64 * j;
        unsigned u = (p < 150) ? yr32[p] : 0u;
        a0[j] = bflo(u); a1[j] = bfhi(u);
    }
    float S0 = 0.f, S1 = 0.f, S2 = 0.f, S3 = 0.f, Sb = 0.f;
    int src = 0;
    float al = 0.f, ea0 = 0.f, ea1 = 0.f, ea2 = 0.f, ea3 = 0.f;
    if (r0 < r1) {
        int e = esort[r0];
        src = ldI(eidx, e, i64);
        al = alpha[e * kH + h];
        ea0 = ldF(eattr, (size_t)e * 4 + 0, f32); ea1 = ldF(eattr, (size_t)e * 4 + 1, f32);
        ea2 = ldF(eattr, (size_t)e * 4 + 2, f32); ea3 = ldF(eattr, (size_t)e * 4 + 3, f32);
    }
    for (int p = r0; p < r1; ++p) {
        int src2 = 0;
        float al2 = 0.f, eb0 = 0.f, eb1 = 0.f, eb2 = 0.f, eb3 = 0.f;
        if (p + 1 < r1) {
            int e2 = esort[p + 1];
            src2 = ldI(eidx, e2, i64);
            al2 = alpha[e2 * kH + h];
            eb0 = ldF(eattr, (size_t)e2 * 4 + 0, f32); eb1 = ldF(eattr, (size_t)e2 * 4 + 1, f32);
            eb2 = ldF(eattr, (size_t)e2 * 4 + 2, f32); eb3 = ldF(eattr, (size_t)e2 * 4 + 3, f32);
        }
        float coeff = al * inv;
        S0 += coeff * ea0; S1 += coeff * ea1; S2 += coeff * ea2; S3 += coeff * ea3;
        Sb += coeff;
        const unsigned* vr = (const unsigned*)(vb + (size_t)src * kHC + h * kD);
#pragma unroll
        for (int j = 0; j < 3; ++j) {
            int pp = lane + 64 * j;
            if (pp < 150) {
                unsigned u = vr[pp];
                a0[j] += coeff * bflo(u);
                a1[j] += coeff * bfhi(u);
            }
        }
        src = src2; al = al2; ea0 = eb0; ea1 = eb1; ea2 = eb2; ea3 = eb3;
    }
    {
        const float* wb = Wef + h * kD;
        const float* br = bef + h * kD;
#pragma unroll
        for (int j = 0; j < 3; ++j) {
            int p = lane + 64 * j;
            if (p < 150) {
                int c0 = 2 * p, c1 = 2 * p + 1;
                a0[j] += S0 * wb[c0] + S1 * wb[kHC + c0] + S2 * wb[2 * kHC + c0] +
                         S3 * wb[3 * kHC + c0] + Sb * br[c0];
                a1[j] += S0 * wb[c1] + S1 * wb[kHC + c1] + S2 * wb[2 * kHC + c1] +
                         S3 * wb[3 * kHC + c1] + Sb * br[c1];
            }
        }
    }
    float s = 0.f, s2 = 0.f;
#pragma unroll
    for (int j = 0; j < 3; ++j) {
        s += a0[j] + a1[j];
        s2 += a0[j] * a0[j] + a1[j] * a1[j];
    }
#pragma unroll
    for (int off = 32; off > 0; off >>= 1) {
        s += __shfl_down(s, off);
        s2 += __shfl_down(s2, off);
    }
    __shared__ float ss[4], ss2[4];
    if (lane == 0) { ss[h] = s; ss2[h] = s2; }
    __syncthreads();
    if (t == 0) {
        float S = ss[0] + ss[1] + ss[2] + ss[3];
        float S2 = ss2[0] + ss2[1] + ss2[2] + ss2[3];
        float mean = S / (float)kHC;
        float var = S2 / (float)kHC - mean * mean;
        ss[0] = mean;
        ss2[0] = rsqrtf(var + 1e-5f);
    }
    __syncthreads();
    float mean = ss[0], rstd = ss2[0];
#pragma unroll
    for (int j = 0; j < 3; ++j) {
        int p = lane + 64 * j;
        if (p < 150) {
            int c0 = h * kD + 2 * p;
            float v0 = lnaf[c0] * (a0[j] - mean) * rstd + lnbf[c0];
            float v1 = lnaf[c0 + 1] * (a1[j] - mean) * rstd + lnbf[c0 + 1];
            yr32[p] = bfpack(v0, v1);
        }
    }
    if (t < kK2 - kHC) yr[kHC + t] = (bf16)0.f;
}

// ---------------- GEMM2: out = elu(y @ Wlin + blin + xin)  (unchanged) ------
__global__ __launch_bounds__(256, 4) void gemm_out(const bf16* __restrict__ Ay,
                                                   const bf16* __restrict__ Bf,
                                                   const float* __restrict__ blinf,
                                                   const void* __restrict__ xin,
                                                   void* __restrict__ out,
                                                   const int* __restrict__ flags) {
    __shared__ alignas(16) bf16 As[64 * 32];
    const int logical = xcd_swz<kWG2>(blockIdx.x);
    const int mb = logical / kNB2, nb = logical % kNB2;
    const int f32 = flags[0];
    const int tid = threadIdx.x;
    const int lane = tid & 63, wave = tid >> 6;
    const int quad = lane >> 4, l16 = lane & 15;
    const int mw = (wave >> 1) * 32;
    const int fibase = (wave & 1) * 4;
    const f32x4 zero = {0.f, 0.f, 0.f, 0.f};
    f32x4 acc[2][4];
#pragma unroll
    for (int i = 0; i < 2; i++)
#pragma unroll
        for (int j = 0; j < 4; j++) acc[i][j] = zero;
    const int mblk = mb * 64, nblk = nb * 128;
    const int srow = wave * 16 + (lane >> 2);
    const int ss = lane & 3;
    const bf16* gA = Ay + (size_t)(mblk + srow) * kLY + ((ss ^ ((srow >> 1) & 3)) << 3);
    bf16* lA = As + wave * 512;
    int aoff[2];
#pragma unroll
    for (int i = 0; i < 2; i++) {
        int ra = mw + i * 16 + l16;
        aoff[i] = ra * 32 + ((quad ^ ((ra >> 1) & 3)) << 3);
    }
    const bf16* bbase = Bf + (size_t)nb * (kT2 * 4096) + fibase * 512 + lane * 8;
    for (int t = 0; t < kT2; ++t) {
        __syncthreads();
        glds16(gA + t * 32, lA);
        bf16x8 bfv[4];
#pragma unroll
        for (int ni = 0; ni < 4; ni++)
            bfv[ni] = *(const bf16x8*)(bbase + (size_t)t * 4096 + ni * 512);
        __syncthreads();
        bf16x8 af[2];
#pragma unroll
        for (int i = 0; i < 2; i++) af[i] = *(const bf16x8*)&As[aoff[i]];
#pragma unroll
        for (int mi = 0; mi < 2; mi++)
#pragma unroll
            for (int ni = 0; ni < 4; ni++)
                acc[mi][ni] = __builtin_amdgcn_mfma_f32_16x16x32_bf16(
                    af[mi], bfv[ni], acc[mi][ni], 0, 0, 0);
    }
#pragma unroll
    for (int mi = 0; mi < 2; mi++)
#pragma unroll
        for (int r = 0; r < 4; r++) {
            int m = mblk + mw + mi * 16 + quad * 4 + r;
            if (m >= kN) continue;
#pragma unroll
            for (int ni = 0; ni < 4; ni++) {
                int n = nblk + (fibase + ni) * 16 + l16;
                if (n >= kD) continue;
                float resid = ldF(xin, (size_t)m * kD + n, f32);
                float t2 = acc[mi][ni][r] + blinf[n] + resid;
                float r2 = t2 > 0.f ? t2 : expm1f(t2);
                if (f32) ((float*)out)[(size_t)m * kD + n] = r2;
                else     ((bf16*)out)[(size_t)m * kD + n] = (bf16)r2;
            }
        }
}

// tripwire: if workspace too small, emit out=xin-bytes (distinctive signature)
__global__ void fallback_copy(const unsigned short* __restrict__ xin_u,
                              unsigned short* __restrict__ out_u) {
    int i = blockIdx.x * 256 + threadIdx.x;
    if (i < kN * kD) out_u[i] = xin_u[i];
}

// ---------------- launch ----------------
extern "C" void kernel_launch(void* const* d_in, const int* in_sizes, int n_in,
                              void* d_out, int out_size, void* d_ws, size_t ws_size,
                              hipStream_t stream) {
    const void* xin  = d_in[0];
    const void* eidx = d_in[1];
    const void* eatt = d_in[2];
    const void* Wq   = d_in[3];
    const void* bq   = d_in[4];
    const void* Wk   = d_in[5];
    const void* bk   = d_in[6];
    const void* Wv   = d_in[7];
    const void* bv   = d_in[8];
    const void* We   = d_in[9];
    const void* be   = d_in[10];
    const void* Wsk  = d_in[11];
    const void* bsk  = d_in[12];
    const void* lna  = d_in[13];
    const void* lnb  = d_in[14];
    const void* Wlin = d_in[15];
    const void* blin = d_in[16];

    char* ws = (char*)d_ws;
    size_t off = 0;
    auto alloc = [&](size_t bytes) -> char* {
        char* p = ws + off;
        off += (bytes + 255) & ~(size_t)255;
        return p;
    };
    bf16* bufA   = (bf16*)alloc((size_t)kMP * kLY * 2);       // 121.7 MB  Z -> s -> y
    bf16* bufB   = (bf16*)alloc((size_t)kN * kHC * 2);        // 120.0 MB  scratch -> v
    bf16* W1f    = (bf16*)alloc((size_t)kNB1 * kT1 * 4096 * 2); // 1.6 MB (skip|v pack)
    float* bcat  = (float*)alloc((size_t)kNP1 * 4);
    bf16* W2f    = (bf16*)alloc((size_t)kN2P * kK2 * 2);      //   0.9 MB
    float* alpha = (float*)alloc((size_t)kE * kH * 4);        //   1.6 MB
    char* ovl    = alloc(kXhiBytes);                          // 400,672 B union
    int* cnt     = (int*)ovl;
    int* fill    = (int*)(ovl + 200064);
    bf16* xhi    = (bf16*)ovl;
    int* rowptr  = (int*)alloc((size_t)(kN + 1) * 4);
    int* esort   = (int*)alloc((size_t)kE * 4);
    int* bsum    = (int*)alloc(256 * 4);
    float* Wef   = (float*)alloc((size_t)4 * kHC * 4);
    float* bef   = (float*)alloc((size_t)kHC * 4);
    float* lnaf  = (float*)alloc((size_t)kHC * 4);
    float* lnbf  = (float*)alloc((size_t)kHC * 4);
    float* blinf = (float*)alloc((size_t)kD * 4);
    int* flags   = (int*)alloc(2 * 4);
    (void)in_sizes; (void)n_in;
    // Bilinear scratch lives INSIDE bufB (dead until pass-1 writes v):
    //   Zf pack | Mscr | Uscr | w3 | consts | Tbuf  — all consumed before pass 1.
    char* bscr   = (char*)bufB;
    bf16* Zf     = (bf16*)(bscr);                 //   819,200 B
    float* Mscr  = (float*)(bscr + 819200);       // 1,459,200 B [4][300][304]
    float* Uscr  = (float*)(bscr + 2278400);      //    29,184 B [24][304]
    float* w3scr = (float*)(bscr + 2307584);      //     4,864 B [4][304]
    float* cst8  = (float*)(bscr + 2312448);      //       128 B [4][8]
    bf16* Tb     = (bf16*)(bscr + 2312704);       // 2,400,000 B [kN][24]
    // d_out (dead until gemm_out) holds xpad rows < kSplitRow
    bf16* xlo = (bf16*)d_out;
    if (off > ws_size ||
        (size_t)out_size * 2 < (size_t)kSplitRow * kK1A * 2 + 32) {
        fallback_copy<<<(kN * kD + 255) / 256, 256, 0, stream>>>(
            (const unsigned short*)xin, (unsigned short*)d_out);
        return;
    }

    constexpr int kScanNB = (kN + 255) / 256;                 // 196 blocks
    detect_kernel<<<1, 256, 0, stream>>>((const unsigned short*)xin, (const int*)eidx, flags);
    hipMemsetAsync(cnt, 0, 200064 + (size_t)kN * 4, stream);  // cnt AND fill
    hist_kernel<<<(kE + 255) / 256, 256, 0, stream>>>(eidx, cnt, flags);
    scan_local<<<kScanNB, 256, 0, stream>>>(cnt, rowptr, bsum);
    scan_bsums<<<1, 256, 0, stream>>>(bsum, kScanNB);
    scan_add<<<kScanNB, 256, 0, stream>>>(rowptr, bsum);
    scatter_kernel<<<(kE + 255) / 256, 256, 0, stream>>>(eidx, rowptr, fill, esort, flags);
    cast_xpad<<<((kN + 1) * 76 + 255) / 256, 256, 0, stream>>>(xin, xlo, xhi, flags);
    cast5<<<(4 * kHC + 3 * kHC + kD + 255) / 256, 256, 0, stream>>>(
        We, be, lna, lnb, blin, Wef, bef, lnaf, lnbf, blinf, flags);
    compute_M<<<4 * 19 * 19, 256, 0, stream>>>(Wq, Wk, Mscr, flags);
    compute_U<<<(28 * 304 + 24 + 255) / 256, 256, 0, stream>>>(
        Wq, Wk, We, be, bq, bk, Uscr, w3scr, cst8, flags);
    pack_Zf<<<(kNB0 * kT1 * 8 * 64 + 255) / 256, 256, 0, stream>>>(Mscr, Uscr, Zf);
    pack_W1f<<<(kNB1 * kT1 * 8 * 64 + 255) / 256, 256, 0, stream>>>(Wsk, Wv, W1f, flags);
    pack_bias<<<(kNP1 + 255) / 256, 256, 0, stream>>>(bsk, bv, bcat, flags);
    pack_W2f<<<(kNB2 * kT2 * 8 * 64 + 255) / 256, 256, 0, stream>>>(Wlin, W2f, flags);

    // pass 0: Z -> bufA, T -> Tb   (N=1280, XCD-swizzled)
    gemm_z<<<kWG0, 256, 0, stream>>>(xlo, xhi, Zf, bufA, Tb);
    // per-node alpha: z_dst . x_src gather (x L3-resident); inv -> bufA cols 1200+
    node_alpha<<<kN, 256, 0, stream>>>(rowptr, esort, eidx, eatt, bufA, xlo, xhi,
                                       Tb, w3scr, cst8, alpha, flags);
    // pass 1: skip -> bufA (cols<1200), v -> bufB (overwrites scratch)
    gemm_qkvs<<<kWG1, 256, 0, stream>>>(xlo, xhi, W1f, bcat, bufA, bufB);
    node_fused<<<kMP, 256, 0, stream>>>(rowptr, esort, eidx, eatt, Wef, bef, alpha,
                                        bufB, lnaf, lnbf, bufA, flags);
    gemm_out<<<kWG2, 256, 0, stream>>>(bufA, W2f, blinf, xin, d_out, flags);
}

// Round 13
// 1028.287 us; speedup vs baseline: 1.1283x; 1.1283x over previous
//
#include <hip/hip_runtime.h>
#include <hip/hip_bf16.h>

typedef __bf16 bf16;
typedef __bf16 bf16x4 __attribute__((ext_vector_type(4)));
typedef __bf16 bf16x8 __attribute__((ext_vector_type(8)));
typedef float f32x4 __attribute__((ext_vector_type(4)));

constexpr int kN = 50000;      // nodes
constexpr int kE = 100000;     // edges
constexpr int kD = 300;        // node dim / per-head dim
constexpr int kH = 4;          // heads
constexpr int kHC = 1200;      // kH*kD
constexpr int kK1A = 304;      // xpad row stride (bf16): 608B, 16B-aligned
constexpr int kK1B = 320;      // W1 K padded: cols k>=300 zero => kills A tail garbage
constexpr int kNP1 = 2432;     // pass-1 N (skip|v: 2*1200 -> 19*128)
constexpr int kNZ  = 1280;     // pass-0 N (Z 1200 + T 24 -> 10*128)
constexpr int kTW  = 24;       // T buffer width (4 heads x 6 cols)
constexpr int kMP = 50048;     // M padded
constexpr int kK2 = 1216;      // K padded for GEMM2 (1200->1216)
constexpr int kN2P = 384;      // N padded for GEMM2 (300->384)
constexpr int kLY = 1216;      // bufA row stride (z/s/y)
constexpr int kNB1 = kNP1 / 128;   // 19 n-blocks (pass-1)
constexpr int kNB0 = kNZ / 128;    // 10 n-blocks (pass-0)
constexpr int kMB2 = kMP / 64;     // 782 m-blocks (64-row tiles)
constexpr int kT1 = kK1B / 32;     // 10 K-steps (GEMM1)
constexpr int kNB2 = kN2P / 128;   // 3 n-blocks (GEMM2)
constexpr int kT2 = kK2 / 32;      // 38 K-steps (GEMM2)
constexpr int kWG1 = kMB2 * kNB1;  // 14858 blocks (pass-1)
constexpr int kWG0 = kMB2 * kNB0;  // 7820 blocks (pass-0)
constexpr int kWG2 = kMB2 * kNB2;  // 2346 blocks (GEMM2)
constexpr int kEW = 136;           // epilogue LDS row stride
// xpad split: rows < kSplitRow in d_out, rest in ws region unioned with cnt/fill
constexpr int kSplitRow = 49342;             // 49342*608 = 29,999,936 <= 30,000,000
constexpr size_t kXhiBytes = (size_t)(kN + 1 - kSplitRow) * kK1A * 2;  // 400,672

// ---- dtype-agnostic loads (flags[0]: floats are fp32; flags[1]: ints are int64)
__device__ __forceinline__ float ldF(const void* p, size_t i, int f32) {
    return f32 ? ((const float*)p)[i] : (float)((const bf16*)p)[i];
}
__device__ __forceinline__ int ldI(const void* p, size_t i, int i64) {
    return i64 ? ((const int*)p)[2 * i] : ((const int*)p)[i];
}

// split-xpad row pointer
__device__ __forceinline__ const bf16* xrow(const bf16* lo, const bf16* hi, int r) {
    return r < kSplitRow ? lo + (size_t)r * kK1A : hi + (size_t)(r - kSplitRow) * kK1A;
}
__device__ __forceinline__ bf16* xrow_w(bf16* lo, bf16* hi, int r) {
    return r < kSplitRow ? lo + (size_t)r * kK1A : hi + (size_t)(r - kSplitRow) * kK1A;
}

// ---- async global->LDS, 16B per lane. LDS dest = wave-uniform base + lane*16.
__device__ __forceinline__ void glds16(const void* g, void* l) {
    __builtin_amdgcn_global_load_lds((const __attribute__((address_space(1))) void*)g,
                                     (__attribute__((address_space(3))) void*)l, 16, 0, 0);
}

// ---- XCD-aware bijective block swizzle (T1, m204)
template <int NWG>
__device__ __forceinline__ int xcd_swz(int phys) {
    constexpr int q = NWG >> 3, r = NWG & 7;
    int xcd = phys & 7, i = phys >> 3;
    int base = xcd < r ? xcd * (q + 1) : r * (q + 1) + (xcd - r) * q;
    return base + i;
}

// ---- bf16-pair (u32) helpers
__device__ __forceinline__ float bflo(unsigned u) {
    return __builtin_bit_cast(float, u << 16);
}
__device__ __forceinline__ float bfhi(unsigned u) {
    return __builtin_bit_cast(float, u & 0xFFFF0000u);
}
__device__ __forceinline__ unsigned bfpack(float a, float b) {
    bf16 x = (bf16)a, y = (bf16)b;
    unsigned short ux = __builtin_bit_cast(unsigned short, x);
    unsigned short uy = __builtin_bit_cast(unsigned short, y);
    return (unsigned)ux | ((unsigned)uy << 16);
}
// wave-wide sum, result on all lanes
__device__ __forceinline__ float wsum(float v) {
#pragma unroll
    for (int o = 32; o > 0; o >>= 1) v += __shfl_xor(v, o);
    return v;
}

// ---------------- dtype detector (device-side, graph-safe) ----------------
__global__ void detect_kernel(const unsigned short* __restrict__ xin_u,
                              const int* __restrict__ eidx_i,
                              int* __restrict__ flags) {
    __shared__ int s_ff, s_nz;
    if (threadIdx.x == 0) { s_ff = 0; s_nz = 0; }
    __syncthreads();
    int c1 = 0;
    for (int i = threadIdx.x; i < 65536; i += 256)
        c1 += (((xin_u[i] >> 7) & 0xFF) == 0xFF);   // bf16-view exp==0xFF => data is fp32
    int c2 = 0;
    for (int i = threadIdx.x; i < 1024; i += 256)
        c2 += (eidx_i[2 * i + 1] != 0);             // odd words all zero => int64
    atomicAdd(&s_ff, c1);
    atomicAdd(&s_nz, c2);
    __syncthreads();
    if (threadIdx.x == 0) {
        flags[0] = (s_ff > 0) ? 1 : 0;
        flags[1] = (s_nz == 0) ? 1 : 0;
    }
}

// ---------------- merged small-casts ----------------
__global__ void cast5(const void* __restrict__ We, const void* __restrict__ be,
                      const void* __restrict__ lna, const void* __restrict__ lnb,
                      const void* __restrict__ blin, float* __restrict__ Wef,
                      float* __restrict__ bef, float* __restrict__ lnaf,
                      float* __restrict__ lnbf, float* __restrict__ blinf,
                      const int* __restrict__ flags) {
    int i = blockIdx.x * 256 + threadIdx.x;
    int f32 = flags[0];
    if (i < 4 * kHC) { Wef[i] = ldF(We, i, f32); return; }
    i -= 4 * kHC;
    if (i < kHC) { bef[i] = ldF(be, i, f32); return; }
    i -= kHC;
    if (i < kHC) { lnaf[i] = ldF(lna, i, f32); return; }
    i -= kHC;
    if (i < kHC) { lnbf[i] = ldF(lnb, i, f32); return; }
    i -= kHC;
    if (i < kD) blinf[i] = ldF(blin, i, f32);
}

// ---------------- xin -> bf16 split-padded [kN+1][304] ----------------
__global__ void cast_xpad(const void* __restrict__ xin, bf16* __restrict__ xlo,
                          bf16* __restrict__ xhi, const int* __restrict__ flags) {
    int idx = blockIdx.x * 256 + threadIdx.x;      // one thread per 4-col chunk
    if (idx < 4) {   // 32B zero guard past last d_out row
        bf16x4 z = {};
        *(bf16x4*)&xlo[(size_t)kSplitRow * kK1A + idx * 4] = z;
    }
    if (idx >= (kN + 1) * 76) return;
    int r = idx / 76, c4 = idx % 76;
    int c = c4 * 4;
    bf16x4 w = {};
    if (r < kN && c < kD) {                         // cols 300..303 and row kN stay 0
        int f32 = flags[0];
        size_t b = (size_t)r * kD + c;
        w[0] = (bf16)ldF(xin, b + 0, f32);
        w[1] = (bf16)ldF(xin, b + 1, f32);
        w[2] = (bf16)ldF(xin, b + 2, f32);
        w[3] = (bf16)ldF(xin, b + 3, f32);
    }
    *(bf16x4*)&(xrow_w(xlo, xhi, r)[c]) = w;        // 8B-aligned (stride 608B)
}

// ---------------- bilinear precompute: M_h = Wq_h Wk_h^T (LDS-tiled GEMM) ----
// [R12 scalar version was a 214us pointer-chase (VALU 3.3%, HBM 0.8%).]
// Grid: 4 heads x 5x5 tiles of 64x64; 256 thr; K-chunks of 32 staged coalesced
// into padded LDS; each thread owns a 4x4 micro-tile (float4 LDS reads).
__global__ __launch_bounds__(256) void compute_M(const void* __restrict__ Wq,
                                                 const void* __restrict__ Wk,
                                                 float* __restrict__ Mscr,
                                                 const int* __restrict__ flags) {
    __shared__ float As[64][36];   // stride 36 floats = 144B (16B-aligned rows)
    __shared__ float Bs[64][36];
    int b = blockIdx.x;
    int h = b / 25, t2 = b % 25;
    int dblk = (t2 / 5) * 64, pblk = (t2 % 5) * 64;
    int f32 = flags[0];
    int tid = threadIdx.x;
    int ty = tid >> 4, tx = tid & 15;
    float acc[4][4] = {};
    for (int kc = 0; kc < 320; kc += 32) {
        __syncthreads();
        for (int idx = tid; idx < 64 * 32; idx += 256) {
            int row = idx >> 5, c = idx & 31;
            int cc = kc + c;
            int d = dblk + row;
            As[row][c] = (d < 300 && cc < 300)
                ? ldF(Wq, (size_t)d * kHC + h * 300 + cc, f32) : 0.f;
            int dp = pblk + row;
            Bs[row][c] = (dp < 300 && cc < 300)
                ? ldF(Wk, (size_t)dp * kHC + h * 300 + cc, f32) : 0.f;
        }
        __syncthreads();
#pragma unroll
        for (int c4 = 0; c4 < 8; ++c4) {
            f32x4 av[4], bv[4];
#pragma unroll
            for (int i = 0; i < 4; ++i) av[i] = *(const f32x4*)&As[ty * 4 + i][c4 * 4];
#pragma unroll
            for (int j = 0; j < 4; ++j) bv[j] = *(const f32x4*)&Bs[tx * 4 + j][c4 * 4];
#pragma unroll
            for (int i = 0; i < 4; ++i)
#pragma unroll
                for (int j = 0; j < 4; ++j)
#pragma unroll
                    for (int e = 0; e < 4; ++e)
                        acc[i][j] += av[i][e] * bv[j][e];
        }
    }
#pragma unroll
    for (int i = 0; i < 4; ++i) {
        int d = dblk + ty * 4 + i;
        if (d >= 300) continue;
#pragma unroll
        for (int j = 0; j < 4; ++j) {
            int dp = pblk + tx * 4 + j;
            if (dp < 304) Mscr[((size_t)h * 300 + d) * 304 + dp] = acc[i][j];
        }
    }
}

// ---------------- U vectors + w3 + constants for exact bias handling --------
// Uscr[h*6+j][d]: j<4: Wq_h^T We_j,h;  j=4: Wq_h^T be_h;  j=5: Wq_h^T bk_h.
// w3scr[h][d] = sum_c bq[hc+c]*Wk[d][hc+c].  cst8[h*8+j]: j<4 bq.We_j, 4 bq.be, 5 bq.bk.
__global__ void compute_U(const void* __restrict__ Wq, const void* __restrict__ Wk,
                          const void* __restrict__ We, const void* __restrict__ be,
                          const void* __restrict__ bq, const void* __restrict__ bk,
                          float* __restrict__ Uscr, float* __restrict__ w3scr,
                          float* __restrict__ cst8, const int* __restrict__ flags) {
    int t = blockIdx.x * 256 + threadIdx.x;
    int f32 = flags[0];
    if (t < 24 * 304) {
        int vi = t / 304, d = t % 304;
        int h = vi / 6, j = vi % 6;
        float s = 0.f;
        if (d < 300) {
#pragma unroll 4
            for (int c = 0; c < 300; ++c) {
                float a = ldF(Wq, (size_t)d * kHC + h * 300 + c, f32);
                float b = (j < 4) ? ldF(We, (size_t)j * kHC + h * 300 + c, f32)
                        : (j == 4) ? ldF(be, h * 300 + c, f32)
                                   : ldF(bk, h * 300 + c, f32);
                s += a * b;
            }
        }
        Uscr[t] = s;
        return;
    }
    t -= 24 * 304;
    if (t < 4 * 304) {
        int h = t / 304, d = t % 304;
        float s = 0.f;
        if (d < 300) {
#pragma unroll 4
            for (int c = 0; c < 300; ++c)
                s += ldF(bq, h * 300 + c, f32) * ldF(Wk, (size_t)d * kHC + h * 300 + c, f32);
        }
        w3scr[t] = s;
        return;
    }
    t -= 4 * 304;
    if (t < 24) {
        int h = t / 6, j = t % 6;
        float s = 0.f;
#pragma unroll 4
        for (int c = 0; c < 300; ++c) {
            float a = ldF(bq, h * 300 + c, f32);
            float b = (j < 4) ? ldF(We, (size_t)j * kHC + h * 300 + c, f32)
                    : (j == 4) ? ldF(be, h * 300 + c, f32)
                               : ldF(bk, h * 300 + c, f32);
            s += a * b;
        }
        cst8[h * 8 + j] = s;
    }
}

// ---------------- pack Z/T panel (frag-major) from M/U scratch --------------
__global__ void pack_Zf(const float* __restrict__ Mscr, const float* __restrict__ Uscr,
                        bf16* __restrict__ Bf) {
    int idx = blockIdx.x * 256 + threadIdx.x;
    if (idx >= kNB0 * kT1 * 8 * 64) return;
    int lane = idx & 63;
    int fi = (idx >> 6) & 7;
    int ksnb = idx >> 9;
    int ks = ksnb % kT1;
    int nb = ksnb / kT1;
    int n = nb * 128 + fi * 16 + (lane & 15);
    int kbase = ks * 32 + (lane >> 4) * 8;
    bf16x8 w = {};
#pragma unroll
    for (int e = 0; e < 8; ++e) {
        int k = kbase + e;
        float v = 0.f;
        if (k < 300) {
            if (n < kHC) {
                int h = n / 300, dp = n % 300;
                v = Mscr[((size_t)h * 300 + k) * 304 + dp];
            } else if (n < kHC + kTW) {
                v = Uscr[(size_t)(n - kHC) * 304 + k];
            }
        }
        w[e] = (bf16)v;
    }
    *(bf16x8*)&Bf[(size_t)idx * 8] = w;
}

// ---------------- pass-1 weight pack (skip|v, frag-major) -------------------
__global__ void pack_W1f(const void* __restrict__ Ws, const void* __restrict__ Wv,
                         bf16* __restrict__ Bf, const int* __restrict__ flags) {
    int idx = blockIdx.x * 256 + threadIdx.x;
    if (idx >= kNB1 * kT1 * 8 * 64) return;
    int f32 = flags[0];
    int lane = idx & 63;
    int fi = (idx >> 6) & 7;
    int ksnb = idx >> 9;
    int ks = ksnb % kT1;
    int nb = ksnb / kT1;
    int n = nb * 128 + fi * 16 + (lane & 15);
    int kbase = ks * 32 + (lane >> 4) * 8;
    const void* W = nullptr;
    int c = 0;
    if (n < kHC)          { W = Ws; c = n; }
    else if (n < 2 * kHC) { W = Wv; c = n - kHC; }
    bf16x8 w = {};
#pragma unroll
    for (int e = 0; e < 8; ++e) {
        int k = kbase + e;
        float v = 0.f;
        if (W && k < kD) v = ldF(W, (size_t)k * kHC + c, f32);
        w[e] = (bf16)v;
    }
    *(bf16x8*)&Bf[(size_t)idx * 8] = w;
}

__global__ void pack_W2f(const void* __restrict__ Wlin, bf16* __restrict__ Bf,
                         const int* __restrict__ flags) {
    int idx = blockIdx.x * 256 + threadIdx.x;
    if (idx >= kNB2 * kT2 * 8 * 64) return;
    int f32 = flags[0];
    int lane = idx & 63;
    int fi = (idx >> 6) & 7;
    int ksnb = idx >> 9;
    int ks = ksnb % kT2;
    int nb = ksnb / kT2;
    int n = nb * 128 + fi * 16 + (lane & 15);
    int kbase = ks * 32 + (lane >> 4) * 8;
    bf16x8 w = {};
#pragma unroll
    for (int e = 0; e < 8; ++e) {
        int k = kbase + e;
        float v = 0.f;
        if (n < kD && k < kHC) v = ldF(Wlin, (size_t)k * kD + n, f32);
        w[e] = (bf16)v;
    }
    *(bf16x8*)&Bf[(size_t)idx * 8] = w;
}

__global__ void pack_bias(const void* __restrict__ bs, const void* __restrict__ bv,
                          float* __restrict__ bcat, const int* __restrict__ flags) {
    int n = blockIdx.x * 256 + threadIdx.x;
    if (n >= kNP1) return;
    int f32 = flags[0];
    float v = 0.f;
    if (n < kHC)          v = ldF(bs, n, f32);
    else if (n < 2 * kHC) v = ldF(bv, n - kHC, f32);
    bcat[n] = v;
}

// ---------------- CSR build (dst-sorted edges) ----------------
__global__ void hist_kernel(const void* __restrict__ eidx, int* __restrict__ cnt,
                            const int* __restrict__ flags) {
    int e = blockIdx.x * 256 + threadIdx.x;
    if (e < kE) atomicAdd(&cnt[ldI(eidx, (size_t)kE + e, flags[1])], 1);
}

__global__ void scan_local(const int* __restrict__ cnt, int* __restrict__ rowptr,
                           int* __restrict__ bsum) {
    int b = blockIdx.x, t = threadIdx.x;
    int i = b * 256 + t;
    int v = (i < kN) ? cnt[i] : 0;
    int lane = t & 63, wv = t >> 6;
    int s = v;
#pragma unroll
    for (int o = 1; o < 64; o <<= 1) {
        int u = __shfl_up(s, o);
        if (lane >= o) s += u;
    }
    __shared__ int wtot[4];
    if (lane == 63) wtot[wv] = s;
    __syncthreads();
    int add = 0;
    for (int w = 0; w < wv; ++w) add += wtot[w];
    if (i < kN) rowptr[i] = s - v + add;
    if (t == 255) bsum[b] = add + s;
}
__global__ void scan_bsums(int* __restrict__ bsum, int nb) {
    int t = threadIdx.x;
    int v = (t < nb) ? bsum[t] : 0;
    int lane = t & 63, wv = t >> 6;
    int s = v;
#pragma unroll
    for (int o = 1; o < 64; o <<= 1) {
        int u = __shfl_up(s, o);
        if (lane >= o) s += u;
    }
    __shared__ int wtot[4];
    if (lane == 63) wtot[wv] = s;
    __syncthreads();
    int add = 0;
    for (int w = 0; w < wv; ++w) add += wtot[w];
    if (t < nb) bsum[t] = s - v + add;
}
__global__ void scan_add(int* __restrict__ rowptr, const int* __restrict__ bsum) {
    int i = blockIdx.x * 256 + threadIdx.x;
    if (i < kN) rowptr[i] += bsum[i >> 8];
    if (i == 0) rowptr[kN] = kE;
}

__global__ void scatter_kernel(const void* __restrict__ eidx, const int* __restrict__ rowptr,
                               int* __restrict__ fill, int* __restrict__ esort,
                               const int* __restrict__ flags) {
    int e = blockIdx.x * 256 + threadIdx.x;
    if (e < kE) {
        int d = ldI(eidx, (size_t)kE + e, flags[1]);
        int pos = rowptr[d] + atomicAdd(&fill[d], 1);
        esort[pos] = e;
    }
}

// ---------------- pass-0 GEMM: [Z|T] = xpad @ [M|U]  (R9-proven structure) ---
__global__ __launch_bounds__(256, 4) void gemm_z(const bf16* __restrict__ xlo,
                                                 const bf16* __restrict__ xhi,
                                                 const bf16* __restrict__ Bf,
                                                 bf16* __restrict__ outA,
                                                 bf16* __restrict__ Tb) {
    __shared__ alignas(16) bf16 As[64 * 32];
    __shared__ alignas(16) bf16 Es[64 * kEW];
    const int logical = xcd_swz<kWG0>(blockIdx.x);
    const int mb = logical / kNB0, nb = logical % kNB0;
    const int tid = threadIdx.x;
    const int lane = tid & 63, wave = tid >> 6;
    const int quad = lane >> 4, l16 = lane & 15;
    const int mw = (wave >> 1) * 32;
    const int fibase = (wave & 1) * 4;
    const f32x4 zero = {0.f, 0.f, 0.f, 0.f};
    f32x4 acc[2][4];
#pragma unroll
    for (int i = 0; i < 2; i++)
#pragma unroll
        for (int j = 0; j < 4; j++) acc[i][j] = zero;
    const int mblk = mb * 64, nblk = nb * 128;
    const int srow = wave * 16 + (lane >> 2);
    const int ss = lane & 3;
    int gr = mblk + srow; if (gr >= kN) gr = kN - 1;
    const bf16* gA = xrow(xlo, xhi, gr) + ((ss ^ ((srow >> 1) & 3)) << 3);
    bf16* lA = As + wave * 512;
    int aoff[2];
#pragma unroll
    for (int i = 0; i < 2; i++) {
        int ra = mw + i * 16 + l16;
        aoff[i] = ra * 32 + ((quad ^ ((ra >> 1) & 3)) << 3);
    }
    const bf16* bbase = Bf + (size_t)nb * (kT1 * 4096) + fibase * 512 + lane * 8;
    for (int t = 0; t < kT1; ++t) {
        __syncthreads();
        glds16(gA + t * 32, lA);
        bf16x8 bfv[4];
#pragma unroll
        for (int ni = 0; ni < 4; ni++)
            bfv[ni] = *(const bf16x8*)(bbase + (size_t)t * 4096 + ni * 512);
        __syncthreads();
        bf16x8 af[2];
#pragma unroll
        for (int i = 0; i < 2; i++) af[i] = *(const bf16x8*)&As[aoff[i]];
#pragma unroll
        for (int mi = 0; mi < 2; mi++)
#pragma unroll
            for (int ni = 0; ni < 4; ni++)
                acc[mi][ni] = __builtin_amdgcn_mfma_f32_16x16x32_bf16(
                    af[mi], bfv[ni], acc[mi][ni], 0, 0, 0);
    }
    __syncthreads();
#pragma unroll
    for (int mi = 0; mi < 2; mi++)
#pragma unroll
        for (int r = 0; r < 4; r++) {
            int lr = mw + mi * 16 + quad * 4 + r;
#pragma unroll
            for (int ni = 0; ni < 4; ni++) {
                int lc = (fibase + ni) * 16 + l16;
                Es[lr * kEW + lc] = (bf16)acc[mi][ni][r];   // no bias on Z/T
            }
        }
    __syncthreads();
#pragma unroll
    for (int it = 0; it < 4; ++it) {
        int row = it * 16 + (tid >> 4);
        int col8 = (tid & 15) * 8;
        int m = mblk + row;
        if (m >= kN) continue;
        bf16x8 w = *(const bf16x8*)&Es[row * kEW + col8];
        int n = nblk + col8;
        if (n < kHC)            *(bf16x8*)&outA[(size_t)m * kLY + n] = w;
        else if (n < kHC + kTW) *(bf16x8*)&Tb[(size_t)m * kTW + (n - kHC)] = w;
    }
}

// ---------------- pass-1 GEMM: [skip|v] = xpad @ W1 + b  (R9-proven) --------
__global__ __launch_bounds__(256, 4) void gemm_qkvs(const bf16* __restrict__ xlo,
                                                    const bf16* __restrict__ xhi,
                                                    const bf16* __restrict__ Bf,
                                                    const float* __restrict__ bcat,
                                                    bf16* __restrict__ outA,
                                                    bf16* __restrict__ outB) {
    __shared__ alignas(16) bf16 As[64 * 32];
    __shared__ alignas(16) bf16 Es[64 * kEW];
    const int logical = xcd_swz<kWG1>(blockIdx.x);
    const int mb = logical / kNB1, nb = logical % kNB1;
    const int tid = threadIdx.x;
    const int lane = tid & 63, wave = tid >> 6;
    const int quad = lane >> 4, l16 = lane & 15;
    const int mw = (wave >> 1) * 32;
    const int fibase = (wave & 1) * 4;
    const f32x4 zero = {0.f, 0.f, 0.f, 0.f};
    f32x4 acc[2][4];
#pragma unroll
    for (int i = 0; i < 2; i++)
#pragma unroll
        for (int j = 0; j < 4; j++) acc[i][j] = zero;
    const int mblk = mb * 64, nblk = nb * 128;
    const int srow = wave * 16 + (lane >> 2);
    const int ss = lane & 3;
    int gr = mblk + srow; if (gr >= kN) gr = kN - 1;
    const bf16* gA = xrow(xlo, xhi, gr) + ((ss ^ ((srow >> 1) & 3)) << 3);
    bf16* lA = As + wave * 512;
    int aoff[2];
#pragma unroll
    for (int i = 0; i < 2; i++) {
        int ra = mw + i * 16 + l16;
        aoff[i] = ra * 32 + ((quad ^ ((ra >> 1) & 3)) << 3);
    }
    const bf16* bbase = Bf + (size_t)nb * (kT1 * 4096) + fibase * 512 + lane * 8;
    for (int t = 0; t < kT1; ++t) {
        __syncthreads();
        glds16(gA + t * 32, lA);
        bf16x8 bfv[4];
#pragma unroll
        for (int ni = 0; ni < 4; ni++)
            bfv[ni] = *(const bf16x8*)(bbase + (size_t)t * 4096 + ni * 512);
        __syncthreads();
        bf16x8 af[2];
#pragma unroll
        for (int i = 0; i < 2; i++) af[i] = *(const bf16x8*)&As[aoff[i]];
#pragma unroll
        for (int mi = 0; mi < 2; mi++)
#pragma unroll
            for (int ni = 0; ni < 4; ni++)
                acc[mi][ni] = __builtin_amdgcn_mfma_f32_16x16x32_bf16(
                    af[mi], bfv[ni], acc[mi][ni], 0, 0, 0);
    }
    __syncthreads();
#pragma unroll
    for (int mi = 0; mi < 2; mi++)
#pragma unroll
        for (int r = 0; r < 4; r++) {
            int lr = mw + mi * 16 + quad * 4 + r;
#pragma unroll
            for (int ni = 0; ni < 4; ni++) {
                int lc = (fibase + ni) * 16 + l16;
                Es[lr * kEW + lc] = (bf16)(acc[mi][ni][r] + bcat[nblk + lc]);
            }
        }
    __syncthreads();
#pragma unroll
    for (int it = 0; it < 4; ++it) {
        int row = it * 16 + (tid >> 4);
        int col8 = (tid & 15) * 8;
        int m = mblk + row;
        if (m >= kN) continue;
        bf16x8 w = *(const bf16x8*)&Es[row * kEW + col8];
        int n = nblk + col8;
        if (n < kHC)          *(bf16x8*)&outA[(size_t)m * kLY + n] = w;
        else if (n < 2 * kHC) *(bf16x8*)&outB[(size_t)m * kHC + (n - kHC)] = w;
    }
}

// ---------------- node_alpha (bilinear form): gather x_src (600B, L3-hot) ----
// logit = z_dst.x_src + w3.x_src + sum_j ea_j*(t_j+c_j) + (t4+c4) + (t5+c5)
// == q.(k+ee) exactly (biases folded via T cols + consts).
__global__ __launch_bounds__(256) void node_alpha(const int* __restrict__ rowptr,
                                                  const int* __restrict__ esort,
                                                  const void* __restrict__ eidx,
                                                  const void* __restrict__ eattr,
                                                  bf16* __restrict__ qb,
                                                  const bf16* __restrict__ xlo,
                                                  const bf16* __restrict__ xhi,
                                                  const bf16* __restrict__ Tb,
                                                  const float* __restrict__ w3scr,
                                                  const float* __restrict__ cst8,
                                                  float* __restrict__ alpha,
                                                  const int* __restrict__ flags) {
    int i = blockIdx.x;
    int h = threadIdx.x >> 6, lane = threadIdx.x & 63;
    int r0 = rowptr[i], r1 = rowptr[i + 1];
    if (r0 >= r1) return;                    // node_fused guards inv by degree
    int f32 = flags[0], i64 = flags[1];
    const unsigned* zr = (const unsigned*)(qb + (size_t)i * kLY + h * kD);
    float z0[3], z1[3], w30[3], w31[3];
#pragma unroll
    for (int j = 0; j < 3; ++j) {
        int p = lane + 64 * j;
        unsigned u = (p < 150) ? zr[p] : 0u;
        z0[j] = bflo(u); z1[j] = bfhi(u);
        if (p < 150) {
            w30[j] = w3scr[h * 304 + 2 * p];
            w31[j] = w3scr[h * 304 + 2 * p + 1];
        } else { w30[j] = 0.f; w31[j] = 0.f; }
    }
    const bf16* tr = Tb + (size_t)i * kTW + h * 6;
    const float* cc = cst8 + h * 8;
    float tj0 = (float)tr[0] + cc[0], tj1 = (float)tr[1] + cc[1];
    float tj2 = (float)tr[2] + cc[2], tj3 = (float)tr[3] + cc[3];
    float base = ((float)tr[4] + cc[4]) + ((float)tr[5] + cc[5]);
    float denom = 0.f;
    for (int p = r0; p < r1; ++p) {
        int e = esort[p];
        int src = ldI(eidx, e, i64);
        float ea0 = ldF(eattr, (size_t)e * 4 + 0, f32), ea1 = ldF(eattr, (size_t)e * 4 + 1, f32);
        float ea2 = ldF(eattr, (size_t)e * 4 + 2, f32), ea3 = ldF(eattr, (size_t)e * 4 + 3, f32);
        const unsigned* xr = (const unsigned*)xrow(xlo, xhi, src);
        float s = 0.f;
#pragma unroll
        for (int j = 0; j < 3; ++j) {
            int pp = lane + 64 * j;
            if (pp < 150) {
                unsigned u = xr[pp];
                float xa = bflo(u), xb = bfhi(u);
                s += (z0[j] + w30[j]) * xa + (z1[j] + w31[j]) * xb;
            }
        }
        float dot = wsum(s);
        float logit = dot + base + ea0 * tj0 + ea1 * tj1 + ea2 * tj2 + ea3 * tj3;
        float a = expf(logit * 0.05773502691896258f);   // 1/sqrt(300)
        if (lane == 0) alpha[e * kH + h] = a;
        denom += a;                                     // wave-uniform
    }
    if (lane == 0)
        ((float*)(qb + (size_t)i * kLY + kHC))[h] = 1.f / (denom + 1e-16f);
}

// ---------------- fused: aggregate + skip + LayerNorm (unchanged, proven) ----
__global__ __launch_bounds__(256) void node_fused(const int* __restrict__ rowptr,
                                                  const int* __restrict__ esort,
                                                  const void* __restrict__ eidx,
                                                  const void* __restrict__ eattr,
                                                  const float* __restrict__ Wef,
                                                  const float* __restrict__ bef,
                                                  const float* __restrict__ alpha,
                                                  const bf16* __restrict__ vb,
                                                  const float* __restrict__ lnaf,
                                                  const float* __restrict__ lnbf,
                                                  bf16* __restrict__ qy,
                                                  const int* __restrict__ flags) {
    int i = blockIdx.x;
    int t = threadIdx.x, h = t >> 6, lane = t & 63;
    bf16* yr = qy + (size_t)i * kLY;
    if (i >= kN) {
        for (int c = t; c < kK2; c += 256) yr[c] = (bf16)0.f;
        return;
    }
    int f32 = flags[0], i64 = flags[1];
    int r0 = rowptr[i], r1 = rowptr[i + 1];
    float inv = (r1 > r0) ? ((const float*)(yr + kHC))[h] : 0.f;
    unsigned* yr32 = (unsigned*)(yr + h * kD);
    float a0[3], a1[3];
#pragma unroll
    for (int j = 0; j < 3; ++j) {
        int p = lane + 64 * j;
        unsigned u = (p < 150) ? yr32[p] : 0u;
        a0[j] = bflo(u); a1[j] = bfhi(u);
    }
    float S0 = 0.f, S1 = 0.f, S2 = 0.f, S3 = 0.f, Sb = 0.f;
    int src = 0;
    float al = 0.f, ea0 = 0.f, ea1 = 0.f, ea2 = 0.f, ea3 = 0.f;
    if (r0 < r1) {
        int e = esort[r0];
        src = ldI(eidx, e, i64);
        al = alpha[e * kH + h];
        ea0 = ldF(eattr, (size_t)e * 4 + 0, f32); ea1 = ldF(eattr, (size_t)e * 4 + 1, f32);
        ea2 = ldF(eattr, (size_t)e * 4 + 2, f32); ea3 = ldF(eattr, (size_t)e * 4 + 3, f32);
    }
    for (int p = r0; p < r1; ++p) {
        int src2 = 0;
        float al2 = 0.f, eb0 = 0.f, eb1 = 0.f, eb2 = 0.f, eb3 = 0.f;
        if (p + 1 < r1) {
            int e2 = esort[p + 1];
            src2 = ldI(eidx, e2, i64);
            al2 = alpha[e2 * kH + h];
            eb0 = ldF(eattr, (size_t)e2 * 4 + 0, f32); eb1 = ldF(eattr, (size_t)e2 * 4 + 1, f32);
            eb2 = ldF(eattr, (size_t)e2 * 4 + 2, f32); eb3 = ldF(eattr, (size_t)e2 * 4 + 3, f32);
        }
        float coeff = al * inv;
        S0 += coeff * ea0; S1 += coeff * ea1; S2 += coeff * ea2; S3 += coeff * ea3;
        Sb += coeff;
        const unsigned* vr = (const unsigned*)(vb + (size_t)src * kHC + h * kD);
#pragma unroll
        for (int j = 0; j < 3; ++j) {
            int pp = lane + 64 * j;
            if (pp < 150) {
                unsigned u = vr[pp];
                a0[j] += coeff * bflo(u);
                a1[j] += coeff * bfhi(u);
            }
        }
        src = src2; al = al2; ea0 = eb0; ea1 = eb1; ea2 = eb2; ea3 = eb3;
    }
    {
        const float* wb = Wef + h * kD;
        const float* br = bef + h * kD;
#pragma unroll
        for (int j = 0; j < 3; ++j) {
            int p = lane + 64 * j;
            if (p < 150) {
                int c0 = 2 * p, c1 = 2 * p + 1;
                a0[j] += S0 * wb[c0] + S1 * wb[kHC + c0] + S2 * wb[2 * kHC + c0] +
                         S3 * wb[3 * kHC + c0] + Sb * br[c0];
                a1[j] += S0 * wb[c1] + S1 * wb[kHC + c1] + S2 * wb[2 * kHC + c1] +
                         S3 * wb[3 * kHC + c1] + Sb * br[c1];
            }
        }
    }
    float s = 0.f, s2 = 0.f;
#pragma unroll
    for (int j = 0; j < 3; ++j) {
        s += a0[j] + a1[j];
        s2 += a0[j] * a0[j] + a1[j] * a1[j];
    }
#pragma unroll
    for (int off = 32; off > 0; off >>= 1) {
        s += __shfl_down(s, off);
        s2 += __shfl_down(s2, off);
    }
    __shared__ float ss[4], ss2[4];
    if (lane == 0) { ss[h] = s; ss2[h] = s2; }
    __syncthreads();
    if (t == 0) {
        float S = ss[0] + ss[1] + ss[2] + ss[3];
        float S2 = ss2[0] + ss2[1] + ss2[2] + ss2[3];
        float mean = S / (float)kHC;
        float var = S2 / (float)kHC - mean * mean;
        ss[0] = mean;
        ss2[0] = rsqrtf(var + 1e-5f);
    }
    __syncthreads();
    float mean = ss[0], rstd = ss2[0];
#pragma unroll
    for (int j = 0; j < 3; ++j) {
        int p = lane + 64 * j;
        if (p < 150) {
            int c0 = h * kD + 2 * p;
            float v0 = lnaf[c0] * (a0[j] - mean) * rstd + lnbf[c0];
            float v1 = lnaf[c0 + 1] * (a1[j] - mean) * rstd + lnbf[c0 + 1];
            yr32[p] = bfpack(v0, v1);
        }
    }
    if (t < kK2 - kHC) yr[kHC + t] = (bf16)0.f;
}

// ---------------- GEMM2: out = elu(y @ Wlin + blin + xin)  (unchanged) ------
__global__ __launch_bounds__(256, 4) void gemm_out(const bf16* __restrict__ Ay,
                                                   const bf16* __restrict__ Bf,
                                                   const float* __restrict__ blinf,
                                                   const void* __restrict__ xin,
                                                   void* __restrict__ out,
                                                   const int* __restrict__ flags) {
    __shared__ alignas(16) bf16 As[64 * 32];
    const int logical = xcd_swz<kWG2>(blockIdx.x);
    const int mb = logical / kNB2, nb = logical % kNB2;
    const int f32 = flags[0];
    const int tid = threadIdx.x;
    const int lane = tid & 63, wave = tid >> 6;
    const int quad = lane >> 4, l16 = lane & 15;
    const int mw = (wave >> 1) * 32;
    const int fibase = (wave & 1) * 4;
    const f32x4 zero = {0.f, 0.f, 0.f, 0.f};
    f32x4 acc[2][4];
#pragma unroll
    for (int i = 0; i < 2; i++)
#pragma unroll
        for (int j = 0; j < 4; j++) acc[i][j] = zero;
    const int mblk = mb * 64, nblk = nb * 128;
    const int srow = wave * 16 + (lane >> 2);
    const int ss = lane & 3;
    const bf16* gA = Ay + (size_t)(mblk + srow) * kLY + ((ss ^ ((srow >> 1) & 3)) << 3);
    bf16* lA = As + wave * 512;
    int aoff[2];
#pragma unroll
    for (int i = 0; i < 2; i++) {
        int ra = mw + i * 16 + l16;
        aoff[i] = ra * 32 + ((quad ^ ((ra >> 1) & 3)) << 3);
    }
    const bf16* bbase = Bf + (size_t)nb * (kT2 * 4096) + fibase * 512 + lane * 8;
    for (int t = 0; t < kT2; ++t) {
        __syncthreads();
        glds16(gA + t * 32, lA);
        bf16x8 bfv[4];
#pragma unroll
        for (int ni = 0; ni < 4; ni++)
            bfv[ni] = *(const bf16x8*)(bbase + (size_t)t * 4096 + ni * 512);
        __syncthreads();
        bf16x8 af[2];
#pragma unroll
        for (int i = 0; i < 2; i++) af[i] = *(const bf16x8*)&As[aoff[i]];
#pragma unroll
        for (int mi = 0; mi < 2; mi++)
#pragma unroll
            for (int ni = 0; ni < 4; ni++)
                acc[mi][ni] = __builtin_amdgcn_mfma_f32_16x16x32_bf16(
                    af[mi], bfv[ni], acc[mi][ni], 0, 0, 0);
    }
#pragma unroll
    for (int mi = 0; mi < 2; mi++)
#pragma unroll
        for (int r = 0; r < 4; r++) {
            int m = mblk + mw + mi * 16 + quad * 4 + r;
            if (m >= kN) continue;
#pragma unroll
            for (int ni = 0; ni < 4; ni++) {
                int n = nblk + (fibase + ni) * 16 + l16;
                if (n >= kD) continue;
                float resid = ldF(xin, (size_t)m * kD + n, f32);
                float t2 = acc[mi][ni][r] + blinf[n] + resid;
                float r2 = t2 > 0.f ? t2 : expm1f(t2);
                if (f32) ((float*)out)[(size_t)m * kD + n] = r2;
                else     ((bf16*)out)[(size_t)m * kD + n] = (bf16)r2;
            }
        }
}

// tripwire: if workspace too small, emit out=xin-bytes (distinctive signature)
__global__ void fallback_copy(const unsigned short* __restrict__ xin_u,
                              unsigned short* __restrict__ out_u) {
    int i = blockIdx.x * 256 + threadIdx.x;
    if (i < kN * kD) out_u[i] = xin_u[i];
}

// ---------------- launch ----------------
extern "C" void kernel_launch(void* const* d_in, const int* in_sizes, int n_in,
                              void* d_out, int out_size, void* d_ws, size_t ws_size,
                              hipStream_t stream) {
    const void* xin  = d_in[0];
    const void* eidx = d_in[1];
    const void* eatt = d_in[2];
    const void* Wq   = d_in[3];
    const void* bq   = d_in[4];
    const void* Wk   = d_in[5];
    const void* bk   = d_in[6];
    const void* Wv   = d_in[7];
    const void* bv   = d_in[8];
    const void* We   = d_in[9];
    const void* be   = d_in[10];
    const void* Wsk  = d_in[11];
    const void* bsk  = d_in[12];
    const void* lna  = d_in[13];
    const void* lnb  = d_in[14];
    const void* Wlin = d_in[15];
    const void* blin = d_in[16];

    char* ws = (char*)d_ws;
    size_t off = 0;
    auto alloc = [&](size_t bytes) -> char* {
        char* p = ws + off;
        off += (bytes + 255) & ~(size_t)255;
        return p;
    };
    bf16* bufA   = (bf16*)alloc((size_t)kMP * kLY * 2);       // 121.7 MB  Z -> s -> y
    bf16* bufB   = (bf16*)alloc((size_t)kN * kHC * 2);        // 120.0 MB  scratch -> v
    bf16* W1f    = (bf16*)alloc((size_t)kNB1 * kT1 * 4096 * 2); // 1.6 MB (skip|v pack)
    float* bcat  = (float*)alloc((size_t)kNP1 * 4);
    bf16* W2f    = (bf16*)alloc((size_t)kN2P * kK2 * 2);      //   0.9 MB
    float* alpha = (float*)alloc((size_t)kE * kH * 4);        //   1.6 MB
    char* ovl    = alloc(kXhiBytes);                          // 400,672 B union
    int* cnt     = (int*)ovl;
    int* fill    = (int*)(ovl + 200064);
    bf16* xhi    = (bf16*)ovl;
    int* rowptr  = (int*)alloc((size_t)(kN + 1) * 4);
    int* esort   = (int*)alloc((size_t)kE * 4);
    int* bsum    = (int*)alloc(256 * 4);
    float* Wef   = (float*)alloc((size_t)4 * kHC * 4);
    float* bef   = (float*)alloc((size_t)kHC * 4);
    float* lnaf  = (float*)alloc((size_t)kHC * 4);
    float* lnbf  = (float*)alloc((size_t)kHC * 4);
    float* blinf = (float*)alloc((size_t)kD * 4);
    int* flags   = (int*)alloc(2 * 4);
    (void)in_sizes; (void)n_in;
    // Bilinear scratch lives INSIDE bufB (dead until pass-1 writes v):
    //   Zf pack | Mscr | Uscr | w3 | consts | Tbuf  — all consumed before pass 1.
    char* bscr   = (char*)bufB;
    bf16* Zf     = (bf16*)(bscr);                 //   819,200 B
    float* Mscr  = (float*)(bscr + 819200);       // 1,459,200 B [4][300][304]
    float* Uscr  = (float*)(bscr + 2278400);      //    29,184 B [24][304]
    float* w3scr = (float*)(bscr + 2307584);      //     4,864 B [4][304]
    float* cst8  = (float*)(bscr + 2312448);      //       128 B [4][8]
    bf16* Tb     = (bf16*)(bscr + 2312704);       // 2,400,000 B [kN][24]
    // d_out (dead until gemm_out) holds xpad rows < kSplitRow
    bf16* xlo = (bf16*)d_out;
    if (off > ws_size ||
        (size_t)out_size * 2 < (size_t)kSplitRow * kK1A * 2 + 32) {
        fallback_copy<<<(kN * kD + 255) / 256, 256, 0, stream>>>(
            (const unsigned short*)xin, (unsigned short*)d_out);
        return;
    }

    constexpr int kScanNB = (kN + 255) / 256;                 // 196 blocks
    detect_kernel<<<1, 256, 0, stream>>>((const unsigned short*)xin, (const int*)eidx, flags);
    hipMemsetAsync(cnt, 0, 200064 + (size_t)kN * 4, stream);  // cnt AND fill
    hist_kernel<<<(kE + 255) / 256, 256, 0, stream>>>(eidx, cnt, flags);
    scan_local<<<kScanNB, 256, 0, stream>>>(cnt, rowptr, bsum);
    scan_bsums<<<1, 256, 0, stream>>>(bsum, kScanNB);
    scan_add<<<kScanNB, 256, 0, stream>>>(rowptr, bsum);
    scatter_kernel<<<(kE + 255) / 256, 256, 0, stream>>>(eidx, rowptr, fill, esort, flags);
    cast_xpad<<<((kN + 1) * 76 + 255) / 256, 256, 0, stream>>>(xin, xlo, xhi, flags);
    cast5<<<(4 * kHC + 3 * kHC + kD + 255) / 256, 256, 0, stream>>>(
        We, be, lna, lnb, blin, Wef, bef, lnaf, lnbf, blinf, flags);
    compute_M<<<4 * 5 * 5, 256, 0, stream>>>(Wq, Wk, Mscr, flags);
    compute_U<<<(28 * 304 + 24 + 255) / 256, 256, 0, stream>>>(
        Wq, Wk, We, be, bq, bk, Uscr, w3scr, cst8, flags);
    pack_Zf<<<(kNB0 * kT1 * 8 * 64 + 255) / 256, 256, 0, stream>>>(Mscr, Uscr, Zf);
    pack_W1f<<<(kNB1 * kT1 * 8 * 64 + 255) / 256, 256, 0, stream>>>(Wsk, Wv, W1f, flags);
    pack_bias<<<(kNP1 + 255) / 256, 256, 0, stream>>>(bsk, bv, bcat, flags);
    pack_W2f<<<(kNB2 * kT2 * 8 * 64 + 255) / 256, 256, 0, stream>>>(Wlin, W2f, flags);

    // pass 0: Z -> bufA, T -> Tb   (N=1280, XCD-swizzled)
    gemm_z<<<kWG0, 256, 0, stream>>>(xlo, xhi, Zf, bufA, Tb);
    // per-node alpha: z_dst . x_src gather (x L3-resident); inv -> bufA cols 1200+
    node_alpha<<<kN, 256, 0, stream>>>(rowptr, esort, eidx, eatt, bufA, xlo, xhi,
                                       Tb, w3scr, cst8, alpha, flags);
    // pass 1: skip -> bufA (cols<1200), v -> bufB (overwrites scratch)
    gemm_qkvs<<<kWG1, 256, 0, stream>>>(xlo, xhi, W1f, bcat, bufA, bufB);
    node_fused<<<kMP, 256, 0, stream>>>(rowptr, esort, eidx, eatt, Wef, bef, alpha,
                                        bufB, lnaf, lnbf, bufA, flags);
    gemm_out<<<kWG2, 256, 0, stream>>>(bufA, W2f, blinf, xin, d_out, flags);
}